// Round 7
// baseline (192.099 us; speedup 1.0000x reference)
//
#include <hip/hip_runtime.h>
#include <hip/hip_bf16.h>
#include <math.h>

#define TPB 256
#define NC 64            // chunks: 64 x 256 rows (8 tile-blocks of 32)
#define CHROWS 256
#define NPAIRS (NC * (NC + 1) / 2)   // 2080 workgroups

#if defined(__has_builtin)
#  if __has_builtin(__builtin_amdgcn_exp2f)
#    define EXP2F(x) __builtin_amdgcn_exp2f(x)
#  else
#    define EXP2F(x) exp2f(x)
#  endif
#else
#  define EXP2F(x) exp2f(x)
#endif

typedef __attribute__((ext_vector_type(8))) short short8v;   // 8 bf16 (4 VGPRs)
typedef __attribute__((ext_vector_type(16))) float f32x16;   // 32x32 acc

union frag_cast { int4 i; short8v s; };

__device__ __forceinline__ unsigned f2bf(float f) {
    __hip_bfloat16 b = __float2bfloat16(f);
    return (unsigned)*(unsigned short*)&b;
}

// U[i] = normalized, sqrt(log2 e)-prescaled bf16 (x,y,z,0) packed in 8B.
// U[N..N+31] = zero rows (for the upper-half-of-wave zero trick). out = 0.
__global__ __launch_bounds__(TPB) void prep_kernel(const float* __restrict__ v,
                                                   uint2* __restrict__ U,
                                                   float* __restrict__ out, int N) {
    int i = blockIdx.x * TPB + threadIdx.x;
    if (i == 0) out[0] = 0.0f;
    if (i < N) {
        float x = v[3 * i], y = v[3 * i + 1], z = v[3 * i + 2];
        float n = sqrtf(fmaf(x, x, fmaf(y, y, z * z))) + 1e-6f;
        float s = 1.2011224087864498f / n;  // sqrt(log2 e) / (|v| + 1e-6)
        uint2 w;
        w.x = f2bf(x * s) | (f2bf(y * s) << 16);
        w.y = f2bf(z * s);
        U[i] = w;
    }
    if (i < 32) U[N + i] = make_uint2(0u, 0u);
}

// One workgroup per chunk-pair (a<=b). Each 32x32 tile (via mfma_32x32x16_bf16,
// K=3 zero-padded) serves BOTH row-sums (rows in chunk a; per-wave registers,
// shfl-reduced once per row-block) and col-sums (rows in chunk b; lane-local
// per tile, accumulated in LDS, flushed as pure stores). Diagonal pairs (a==b)
// compute the full 8x8 block grid and use row-sums only.
// Partials: row -> pZ[b][chunk a rows]; col -> pZ[a][chunk b rows]. Every
// (slot, chunk) cell written exactly once; final sums all 64 slots per row.
__global__ __launch_bounds__(TPB, 4) void pair_kernel(const uint2* __restrict__ U,
                                                      float* __restrict__ pZ,
                                                      float* __restrict__ pS, int N) {
    __shared__ float colZ[CHROWS], colS[CHROWS];
    int tid = threadIdx.x;
    int lane = tid & 63, wave = tid >> 6, half = lane >> 5, lid = lane & 31;

    // decode upper-triangle pair index -> (a, b)
    int l = blockIdx.x, a = 0, cap = NC;
    while (l >= cap) { l -= cap; ++a; --cap; }
    int b = a + l;
    bool diag = (a == b);

    colZ[tid] = 0.0f;
    colS[tid] = 0.0f;
    __syncthreads();

    int abase = a * CHROWS, bbase = b * CHROWS;
    // per-lane row pointers; upper half of wave reads the zero rows at U[N..]
    const uint2* aptr = U + (half ? (N + lid) : (abase + lid));
    const uint2* bptr = U + (half ? (N + lid) : (bbase + lid));
    int binc = half ? 0 : 32;

    const f32x16 czero = (f32x16)0.0f;

#pragma unroll 1
    for (int R = 0; R < 2; ++R) {
        int rblk = wave + 4 * R;  // row-block (0..7) of chunk a owned this pass
        uint2 aw = aptr[half ? 0 : rblk * 32];
        frag_cast au; au.i = make_int4((int)aw.x, (int)aw.y, 0, 0);
        short8v afrag = au.s;

        float Zp[16], Sp[16];
#pragma unroll
        for (int r = 0; r < 16; ++r) { Zp[r] = 0.0f; Sp[r] = 0.0f; }

#pragma unroll 2
        for (int C = 0; C < 8; ++C) {
            uint2 bw = bptr[C * binc];
            frag_cast bu; bu.i = make_int4((int)bw.x, (int)bw.y, 0, 0);
            f32x16 acc = __builtin_amdgcn_mfma_f32_32x32x16_bf16(afrag, bu.s, czero, 0, 0, 0);

            float czl = 0.0f, csl = 0.0f;
#pragma unroll
            for (int r = 0; r < 16; ++r) {
                float t = acc[r];
                float e = EXP2F(t);   // exp2(t) = exp(s)
                float p = t * e;
                Zp[r] += e;
                Sp[r] += p;
                czl += e;
                csl += p;
            }
            if (!diag) {
                // col = C*32 + (lane&31); halves hold disjoint row subsets,
                // so both halves contribute (2-way same-address LDS atomic).
                atomicAdd(&colZ[C * 32 + lid], czl);
                atomicAdd(&colS[C * 32 + lid], csl);
            }
        }

        // reduce row partials across the 32 lanes of each half, store to slot b
#pragma unroll
        for (int r = 0; r < 16; ++r) {
            float z = Zp[r], s = Sp[r];
#pragma unroll
            for (int m = 1; m <= 16; m <<= 1) {
                z += __shfl_xor(z, m);
                s += __shfl_xor(s, m);
            }
            if (lid == 0) {
                int row = (r & 3) + 8 * (r >> 2) + 4 * half;
                int g = abase + rblk * 32 + row;
                pZ[(size_t)b * N + g] = z;
                pS[(size_t)b * N + g] = s;
            }
        }
    }

    if (!diag) {
        __syncthreads();
        pZ[(size_t)a * N + bbase + tid] = colZ[tid];
        pS[(size_t)a * N + bbase + tid] = colS[tid];
    }
}

// Per-row entropy from the 64 slot partials, then mean-reduce into out[0].
__global__ __launch_bounds__(TPB) void final_kernel(const float* __restrict__ pZ,
                                                    const float* __restrict__ pS,
                                                    float* __restrict__ out, int N) {
    int row = blockIdx.x * TPB + threadIdx.x;
    float contrib = 0.0f;
    if (row < N) {
        float Z = 0.0f, S = 0.0f;
#pragma unroll 4
        for (int s = 0; s < NC; ++s) {
            Z += pZ[(size_t)s * N + row];
            S += pS[(size_t)s * N + row];
        }
        const float LN2 = 0.6931471805599453f;
        // H = ln Z - S_nat/Z - eps*N ; S_nat = ln2 * S' ; ln Z = ln2 * log2 Z
        float H = LN2 * (log2f(Z) - S / Z) - 1e-8f * (float)N;
        contrib = H / (float)N;
    }
    for (int off = 32; off; off >>= 1) contrib += __shfl_down(contrib, off);
    __shared__ float red[TPB / 64];
    if ((threadIdx.x & 63) == 0) red[threadIdx.x >> 6] = contrib;
    __syncthreads();
    if (threadIdx.x == 0) {
        float s = 0.0f;
        for (int w = 0; w < TPB / 64; ++w) s += red[w];
        atomicAdd(out, s);
    }
}

extern "C" void kernel_launch(void* const* d_in, const int* in_sizes, int n_in,
                              void* d_out, int out_size, void* d_ws, size_t ws_size,
                              hipStream_t stream) {
    const float* vel = (const float*)d_in[0];
    // d_in[1] (positions) is unused by the reference math.
    int N = in_sizes[0] / 3;
    float* out = (float*)d_out;

    char* ws = (char*)d_ws;
    uint2* U = (uint2*)ws;                                   // (N+32) * 8 B
    float* pZ = (float*)(ws + (size_t)(N + 32) * sizeof(uint2));  // NC * N floats
    float* pS = pZ + (size_t)NC * N;                              // NC * N floats

    int nb = (N + TPB - 1) / TPB;
    prep_kernel<<<nb, TPB, 0, stream>>>(vel, U, out, N);
    pair_kernel<<<NPAIRS, TPB, 0, stream>>>(U, pZ, pS, N);
    final_kernel<<<nb, TPB, 0, stream>>>(pZ, pS, out, N);
}

// Round 8
// 153.902 us; speedup vs baseline: 1.2482x; 1.2482x over previous
//
#include <hip/hip_runtime.h>
#include <hip/hip_bf16.h>
#include <math.h>

#define TPB 256   // 4 waves per block; each wave owns a 32-row block
#define JCH 16    // j-chunks: grid = 128 x 16 = 2048 blocks = 8 wg/CU, no tail
#define CH 1024   // rows per chunk = 32 tiles exactly

#if defined(__has_builtin)
#  if __has_builtin(__builtin_amdgcn_exp2f)
#    define EXP2F(x) __builtin_amdgcn_exp2f(x)
#  else
#    define EXP2F(x) exp2f(x)
#  endif
#else
#  define EXP2F(x) exp2f(x)
#endif

typedef __attribute__((ext_vector_type(8))) short short8v;   // 8 bf16 (4 VGPRs)
typedef __attribute__((ext_vector_type(16))) float f32x16;   // 32x32 acc

__device__ __forceinline__ unsigned f2bf(float f) {
    __hip_bfloat16 b = __float2bfloat16(f);
    return (unsigned)*(unsigned short*)&b;
}

// One fused kernel: stage normalized bf16 chunk in LDS, MFMA 32x32 tiles
// (K=3 zero-padded; vectors pre-scaled by sqrt(log2 e) so t = s*log2(e)),
// per-tile epilogue accumulates Z = sum exp2(t), S' = sum t*exp2(t).
// C/D layout: col = lane&31, row = (reg&3) + 8*(reg>>2) + 4*(lane>>5).
// Dual-tile unroll: two independent ds_read->MFMA->epilogue chains per iter.
__global__ __launch_bounds__(TPB, 8) void pair_kernel(const float* __restrict__ vel,
                                                      float* __restrict__ partZ,
                                                      float* __restrict__ partS,
                                                      float* __restrict__ out, int N) {
    __shared__ __align__(16) uint4 smem[CH + 1];
    int tid = threadIdx.x;
    int lane = tid & 63, wave = tid >> 6, half = lane >> 5, lid = lane & 31;
    int chunk = blockIdx.y;
    int jbase = chunk * CH;

    if (blockIdx.x == 0 && chunk == 0 && tid == 0) out[0] = 0.0f;  // pre-final init

    // Stage normalized, log2e-prescaled bf16 chunk rows into LDS (16B/row).
    for (int j = tid; j < CH; j += TPB) {
        int g = jbase + j;
        float x = vel[3 * g], y = vel[3 * g + 1], z = vel[3 * g + 2];
        float n = sqrtf(fmaf(x, x, fmaf(y, y, z * z))) + 1e-6f;
        float s = 1.2011224087864498f / n;  // sqrt(log2 e) / (|v| + 1e-6)
        uint4 w;
        w.x = f2bf(x * s) | (f2bf(y * s) << 16);
        w.y = f2bf(z * s);
        w.z = 0u; w.w = 0u;
        smem[j] = w;
    }
    if (tid == 0) smem[CH] = make_uint4(0u, 0u, 0u, 0u);  // zero slot

    // A fragment: this wave's 32 rows in lanes 0..31; upper half & k>=3 zero.
    int rbase = blockIdx.x * 128 + wave * 32;
    short8v afrag = (short8v)0;
    if (half == 0) {
        int g = rbase + lid;
        float x = vel[3 * g], y = vel[3 * g + 1], z = vel[3 * g + 2];
        float n = sqrtf(fmaf(x, x, fmaf(y, y, z * z))) + 1e-6f;
        float s = 1.2011224087864498f / n;
        afrag[0] = (short)f2bf(x * s);
        afrag[1] = (short)f2bf(y * s);
        afrag[2] = (short)f2bf(z * s);
    }
    __syncthreads();

    const char* lds = (const char*)smem;
    int off = half ? (CH * 16) : (lid * 16);  // upper half -> fixed zero slot
    int step = half ? 0 : 512;

    float Zp[16], Sp[16];
#pragma unroll
    for (int r = 0; r < 16; ++r) { Zp[r] = 0.0f; Sp[r] = 0.0f; }
    const f32x16 czero = (f32x16)0.0f;

    for (int t = 0; t < 32; t += 2) {
        short8v b0 = *(const short8v*)(lds + off);
        short8v b1 = *(const short8v*)(lds + off + step);
        off += 2 * step;
        f32x16 acc0 = __builtin_amdgcn_mfma_f32_32x32x16_bf16(afrag, b0, czero, 0, 0, 0);
        f32x16 acc1 = __builtin_amdgcn_mfma_f32_32x32x16_bf16(afrag, b1, czero, 0, 0, 0);
#pragma unroll
        for (int r = 0; r < 16; ++r) {
            float t0 = acc0[r], t1 = acc1[r];
            float e0 = EXP2F(t0);  // exp2(t) = exp(s)
            float e1 = EXP2F(t1);
            Zp[r] += e0;
            Sp[r] = fmaf(t0, e0, Sp[r]);
            Zp[r] += e1;
            Sp[r] = fmaf(t1, e1, Sp[r]);
        }
    }

    // Reduce across the 32 lanes of each half (same row set), store partials.
#pragma unroll
    for (int r = 0; r < 16; ++r) {
        float z = Zp[r], s = Sp[r];
#pragma unroll
        for (int m = 1; m <= 16; m <<= 1) {
            z += __shfl_xor(z, m);
            s += __shfl_xor(s, m);
        }
        if (lid == 0) {
            int row = rbase + (r & 3) + 8 * (r >> 2) + 4 * half;
            partZ[(size_t)chunk * N + row] = z;
            partS[(size_t)chunk * N + row] = s;
        }
    }
}

// Per-row entropy from chunk partials, then mean-reduce into out[0].
__global__ __launch_bounds__(TPB) void final_kernel(const float* __restrict__ partZ,
                                                    const float* __restrict__ partS,
                                                    float* __restrict__ out, int N) {
    int row = blockIdx.x * TPB + threadIdx.x;
    float contrib = 0.0f;
    if (row < N) {
        float Z = 0.f, S = 0.f;
#pragma unroll 4
        for (int c = 0; c < JCH; ++c) {
            Z += partZ[(size_t)c * N + row];
            S += partS[(size_t)c * N + row];
        }
        const float LN2 = 0.6931471805599453f;
        // H = ln Z - S_nat/Z - eps*N ;  S_nat = ln2 * S' ;  ln Z = ln2 * log2 Z
        float H = LN2 * (log2f(Z) - S / Z) - 1e-8f * (float)N;
        contrib = H / (float)N;
    }
    for (int offv = 32; offv; offv >>= 1) contrib += __shfl_down(contrib, offv);
    __shared__ float red[TPB / 64];
    if ((threadIdx.x & 63) == 0) red[threadIdx.x >> 6] = contrib;
    __syncthreads();
    if (threadIdx.x == 0) {
        float s = 0.f;
        for (int w = 0; w < TPB / 64; ++w) s += red[w];
        atomicAdd(out, s);
    }
}

extern "C" void kernel_launch(void* const* d_in, const int* in_sizes, int n_in,
                              void* d_out, int out_size, void* d_ws, size_t ws_size,
                              hipStream_t stream) {
    const float* vel = (const float*)d_in[0];
    // d_in[1] (positions) is unused by the reference math.
    int N = in_sizes[0] / 3;
    float* out = (float*)d_out;

    float* partZ = (float*)d_ws;                 // JCH * N floats (pure stores)
    float* partS = partZ + (size_t)JCH * N;      // JCH * N floats

    dim3 grid(N / 128, JCH);
    pair_kernel<<<grid, TPB, 0, stream>>>(vel, partZ, partS, out, N);
    final_kernel<<<(N + TPB - 1) / TPB, TPB, 0, stream>>>(partZ, partS, out, N);
}

// Round 9
// 91.473 us; speedup vs baseline: 2.1001x; 1.6825x over previous
//
#include <hip/hip_runtime.h>
#include <hip/hip_bf16.h>
#include <math.h>

#define TPB 256   // 4 waves per block; each wave owns a 32-row block
#define JCH 16    // j-chunks: grid = 128 x 16 = 2048 blocks, no tail
#define CH 1024   // rows per chunk = 32 tiles exactly

#if defined(__has_builtin)
#  if __has_builtin(__builtin_amdgcn_exp2f)
#    define EXP2F(x) __builtin_amdgcn_exp2f(x)
#  else
#    define EXP2F(x) exp2f(x)
#  endif
#else
#  define EXP2F(x) exp2f(x)
#endif

typedef __attribute__((ext_vector_type(8))) short short8v;   // 8 bf16 (4 VGPRs)
typedef __attribute__((ext_vector_type(16))) float f32x16;   // 32x32 acc

__device__ __forceinline__ unsigned f2bf(float f) {
    __hip_bfloat16 b = __float2bfloat16(f);
    return (unsigned)*(unsigned short*)&b;
}

// One fused kernel: stage normalized bf16 chunk in LDS, MFMA 32x32 tiles
// (K=3 zero-padded; vectors pre-scaled by sqrt(log2 e) so t = s*log2(e)),
// per-tile epilogue accumulates Z = sum exp2(t), S' = sum t*exp2(t).
// C/D layout: col = lane&31, row = (reg&3) + 8*(reg>>2) + 4*(lane>>5).
// Dual-tile unroll: two independent ds_read->MFMA->epilogue chains per iter.
// launch_bounds(TPB,4): 128 reg/wave budget — dual-tile live set ~100, NO SPILL
// (lb=8 in R8 capped at 64 incl. AGPRs -> 264 MB scratch writes, 2.6x slower).
__global__ __launch_bounds__(TPB, 4) void pair_kernel(const float* __restrict__ vel,
                                                      float* __restrict__ partZ,
                                                      float* __restrict__ partS,
                                                      float* __restrict__ out, int N) {
    __shared__ __align__(16) uint4 smem[CH + 1];
    int tid = threadIdx.x;
    int lane = tid & 63, wave = tid >> 6, half = lane >> 5, lid = lane & 31;
    int chunk = blockIdx.y;
    int jbase = chunk * CH;

    if (blockIdx.x == 0 && chunk == 0 && tid == 0) out[0] = 0.0f;  // pre-final init

    // Stage normalized, log2e-prescaled bf16 chunk rows into LDS (16B/row).
    for (int j = tid; j < CH; j += TPB) {
        int g = jbase + j;
        float x = vel[3 * g], y = vel[3 * g + 1], z = vel[3 * g + 2];
        float n = sqrtf(fmaf(x, x, fmaf(y, y, z * z))) + 1e-6f;
        float s = 1.2011224087864498f / n;  // sqrt(log2 e) / (|v| + 1e-6)
        uint4 w;
        w.x = f2bf(x * s) | (f2bf(y * s) << 16);
        w.y = f2bf(z * s);
        w.z = 0u; w.w = 0u;
        smem[j] = w;
    }
    if (tid == 0) smem[CH] = make_uint4(0u, 0u, 0u, 0u);  // zero slot

    // A fragment: this wave's 32 rows in lanes 0..31; upper half & k>=3 zero.
    int rbase = blockIdx.x * 128 + wave * 32;
    short8v afrag = (short8v)0;
    if (half == 0) {
        int g = rbase + lid;
        float x = vel[3 * g], y = vel[3 * g + 1], z = vel[3 * g + 2];
        float n = sqrtf(fmaf(x, x, fmaf(y, y, z * z))) + 1e-6f;
        float s = 1.2011224087864498f / n;
        afrag[0] = (short)f2bf(x * s);
        afrag[1] = (short)f2bf(y * s);
        afrag[2] = (short)f2bf(z * s);
    }
    __syncthreads();

    const char* lds = (const char*)smem;
    int off = half ? (CH * 16) : (lid * 16);  // upper half -> fixed zero slot
    int step = half ? 0 : 512;

    float Zp[16], Sp[16];
#pragma unroll
    for (int r = 0; r < 16; ++r) { Zp[r] = 0.0f; Sp[r] = 0.0f; }
    const f32x16 czero = (f32x16)0.0f;

    for (int t = 0; t < 32; t += 2) {
        short8v b0 = *(const short8v*)(lds + off);
        short8v b1 = *(const short8v*)(lds + off + step);
        off += 2 * step;
        f32x16 acc0 = __builtin_amdgcn_mfma_f32_32x32x16_bf16(afrag, b0, czero, 0, 0, 0);
        f32x16 acc1 = __builtin_amdgcn_mfma_f32_32x32x16_bf16(afrag, b1, czero, 0, 0, 0);
#pragma unroll
        for (int r = 0; r < 16; ++r) {
            float t0 = acc0[r], t1 = acc1[r];
            float e0 = EXP2F(t0);  // exp2(t) = exp(s)
            float e1 = EXP2F(t1);
            Zp[r] += e0;
            Sp[r] = fmaf(t0, e0, Sp[r]);
            Zp[r] += e1;
            Sp[r] = fmaf(t1, e1, Sp[r]);
        }
    }

    // Reduce across the 32 lanes of each half (same row set), store partials.
#pragma unroll
    for (int r = 0; r < 16; ++r) {
        float z = Zp[r], s = Sp[r];
#pragma unroll
        for (int m = 1; m <= 16; m <<= 1) {
            z += __shfl_xor(z, m);
            s += __shfl_xor(s, m);
        }
        if (lid == 0) {
            int row = rbase + (r & 3) + 8 * (r >> 2) + 4 * half;
            partZ[(size_t)chunk * N + row] = z;
            partS[(size_t)chunk * N + row] = s;
        }
    }
}

// Per-row entropy from chunk partials, then mean-reduce into out[0].
__global__ __launch_bounds__(TPB) void final_kernel(const float* __restrict__ partZ,
                                                    const float* __restrict__ partS,
                                                    float* __restrict__ out, int N) {
    int row = blockIdx.x * TPB + threadIdx.x;
    float contrib = 0.0f;
    if (row < N) {
        float Z = 0.f, S = 0.f;
#pragma unroll 4
        for (int c = 0; c < JCH; ++c) {
            Z += partZ[(size_t)c * N + row];
            S += partS[(size_t)c * N + row];
        }
        const float LN2 = 0.6931471805599453f;
        // H = ln Z - S_nat/Z - eps*N ;  S_nat = ln2 * S' ;  ln Z = ln2 * log2 Z
        float H = LN2 * (log2f(Z) - S / Z) - 1e-8f * (float)N;
        contrib = H / (float)N;
    }
    for (int offv = 32; offv; offv >>= 1) contrib += __shfl_down(contrib, offv);
    __shared__ float red[TPB / 64];
    if ((threadIdx.x & 63) == 0) red[threadIdx.x >> 6] = contrib;
    __syncthreads();
    if (threadIdx.x == 0) {
        float s = 0.f;
        for (int w = 0; w < TPB / 64; ++w) s += red[w];
        atomicAdd(out, s);
    }
}

extern "C" void kernel_launch(void* const* d_in, const int* in_sizes, int n_in,
                              void* d_out, int out_size, void* d_ws, size_t ws_size,
                              hipStream_t stream) {
    const float* vel = (const float*)d_in[0];
    // d_in[1] (positions) is unused by the reference math.
    int N = in_sizes[0] / 3;
    float* out = (float*)d_out;

    float* partZ = (float*)d_ws;                 // JCH * N floats (pure stores)
    float* partS = partZ + (size_t)JCH * N;      // JCH * N floats

    dim3 grid(N / 128, JCH);
    pair_kernel<<<grid, TPB, 0, stream>>>(vel, partZ, partS, out, N);
    final_kernel<<<(N + TPB - 1) / TPB, TPB, 0, stream>>>(partZ, partS, out, N);
}